// Round 8
// baseline (2319.844 us; speedup 1.0000x reference)
//
#include <hip/hip_runtime.h>
#include <math.h>

#define BATCH 32
#define HDIM 128
#define ZDIM 32
#define KSTEPS 6

typedef unsigned short ushort_t;
using bf16x8 = __attribute__((ext_vector_type(8))) short;
using f32x4v = __attribute__((ext_vector_type(4))) float;

__device__ __forceinline__ float softplusf(float x){
    return fmaxf(x, 0.f) + log1pf(expf(-fabsf(x)));
}
__device__ __forceinline__ float logsigf(float x){
    return fminf(x, 0.f) - log1pf(expf(-fabsf(x)));
}
__device__ __forceinline__ float fsig(float x){
    return __builtin_amdgcn_rcpf(1.f + __expf(-x));
}
__device__ __forceinline__ float ftanh(float x){
    x = fminf(fmaxf(x, -15.f), 15.f);
    float e = __expf(2.f * x);
    return (e - 1.f) * __builtin_amdgcn_rcpf(e + 1.f);
}
__device__ __forceinline__ float bf2f(ushort_t u){
    return __uint_as_float(((unsigned)u) << 16);
}
__device__ __forceinline__ ushort_t f2bf(float f){
    unsigned x = __float_as_uint(f);
    unsigned r = (x + 0x7fffu + ((x >> 16) & 1u)) >> 16;
    return (ushort_t)r;
}

// ---------------- weight prep kernels ----------------
__global__ __launch_bounds__(256) void stem1wt_k(const float* __restrict__ W,
                                                 float* __restrict__ Wo){
    int idx = blockIdx.x * 256 + threadIdx.x;   // 9600
    if (idx >= 9600) return;
    int co = idx & 127, tap = idx >> 7;
    Wo[(tap << 7) + co] = W[co * 75 + tap];
}

// OIHW f32 -> [tap][ck][coN][ci32] bf16 (opt. gate-slot permute on co)
__global__ __launch_bounds__(256) void cvtw_k(const float* __restrict__ src,
                                              ushort_t* __restrict__ dst,
                                              int Cfull, int ci_off, int ncs,
                                              int ck_off, int NCHK, int NCO, int permute){
    int idx = blockIdx.x * 256 + threadIdx.x;
    int total = 25 * ncs * NCO * 32;
    if (idx >= total) return;
    int per_tap = ncs * NCO * 32;
    int tap = idx / per_tap;
    int r = idx - tap * per_tap;
    int ckl = r / (NCO * 32);
    int r2 = r - ckl * (NCO * 32);
    int co = r2 >> 5, cl = r2 & 31;
    int s = permute ? ((((co & 63) >> 4) << 6) | ((co >> 6) << 4) | (co & 15)) : co;
    float v = src[((size_t)co * Cfull + ci_off + (ckl << 5) + cl) * 25 + tap];
    dst[(((size_t)(tap * NCHK + ck_off + ckl)) * NCO + s) * 32 + cl] = f2bf(v);
}

// dec1_W [co128][ci32][tap16] f32 -> [tap16][co128][ci32] bf16
__global__ __launch_bounds__(256) void dec1wb_k(const float* __restrict__ W,
                                                ushort_t* __restrict__ Wo){
    int idx = blockIdx.x * 256 + threadIdx.x;      // 65536
    int ci = idx & 31, co = (idx >> 5) & 127, tap = idx >> 12;
    Wo[idx] = f2bf(W[(((co << 5) + ci) << 4) + tap]);
}

// dec2_W [ci128][tap16] f32 -> [tap16][ci128] f32
__global__ __launch_bounds__(256) void dec2wt_k(const float* __restrict__ W,
                                                float* __restrict__ Wo){
    int idx = blockIdx.x * 256 + threadIdx.x;      // 2048
    if (idx >= 2048) return;
    int ci = idx & 127, tap = idx >> 7;
    Wo[idx] = W[(ci << 4) + tap];
}

// ---------------- stem1: conv 5x5 s2, 3->128, 128x128 -> 64x64, ReLU, out NHWC bf16
__global__ __launch_bounds__(256) void stem1_k(const float* __restrict__ x,
                                               const float* __restrict__ WtT, // [tap75][co128]
                                               const float* __restrict__ bias,
                                               ushort_t* __restrict__ h1n){
    __shared__ float ws[75 * 128];
    __shared__ float xs[3][5][36];
    const int n = blockIdx.y, pb = blockIdx.x;
    const int oy = pb >> 2, oxb = (pb & 3) << 4;
    const int tid = threadIdx.x;
    const int co = tid & 127, ps = tid >> 7;
    for (int i = tid; i < 9600; i += 256) ws[i] = WtT[i];
    for (int idx = tid; idx < 525; idx += 256){
        int ci = idx / 175, r = (idx - ci * 175) / 35, c = idx - ci * 175 - r * 35;
        int iy = 2 * oy - 1 + r, ix = 2 * oxb - 1 + c;
        float v = 0.f;
        if ((unsigned)iy < 128u && (unsigned)ix < 128u)
            v = x[(size_t)n * 49152 + (ci << 14) + (iy << 7) + ix];
        xs[ci][r][c] = v;
    }
    __syncthreads();
    float b = bias[co];
    float acc[8];
    #pragma unroll
    for (int t = 0; t < 8; ++t) acc[t] = b;
    #pragma unroll
    for (int ci = 0; ci < 3; ++ci){
        #pragma unroll
        for (int ky = 0; ky < 5; ++ky){
            const float* row = &xs[ci][ky][0];
            #pragma unroll
            for (int kx = 0; kx < 5; ++kx){
                float wv = ws[((ci * 25 + ky * 5 + kx) << 7) + co];
                #pragma unroll
                for (int t = 0; t < 8; ++t)
                    acc[t] = fmaf(row[4 * t + 2 * ps + kx], wv, acc[t]);
            }
        }
    }
    #pragma unroll
    for (int t = 0; t < 8; ++t){
        int pix = (oy << 6) + oxb + (t << 1) + ps;
        h1n[((((size_t)n << 12) + pix) << 7) + co] = f2bf(fmaxf(acc[t], 0.f));
    }
}

// ---------------- stem2 MFMA: conv 5x5 s2 SAME, 128->128, 64x64 -> 32x32, ReLU, out bf16
#define S2CP 40
__global__ __launch_bounds__(256) void s2m_k(const ushort_t* __restrict__ h1n,
                                             const ushort_t* __restrict__ wb, // [25][4][128][32]
                                             const float* __restrict__ bias,
                                             ushort_t* __restrict__ h2n){
    __shared__ ushort_t sm[7 * 67 * S2CP];
    const int pb = blockIdx.x, n = blockIdx.y;
    const int tid = threadIdx.x, lane = tid & 63, wv = tid >> 6;
    const int ry = wv >> 1, ch_half = wv & 1;
    const int lm = lane & 15, lg = lane >> 4;

    f32x4v z4 = {0.f, 0.f, 0.f, 0.f};
    f32x4v acc[2][4];
    #pragma unroll
    for (int j = 0; j < 2; ++j)
        #pragma unroll
        for (int cf = 0; cf < 4; ++cf) acc[j][cf] = z4;

    for (int ck = 0; ck < 4; ++ck){
        __syncthreads();
        for (int idx = tid; idx < 7 * 67 * 4; idx += 256){
            int ci8 = idx & 3, cell = idx >> 2;
            int r = cell / 67, c = cell - r * 67;
            int iy = (pb << 2) - 1 + r, ix = c - 1;
            bf16x8 v = {0,0,0,0,0,0,0,0};
            if ((unsigned)iy < 64u && (unsigned)ix < 64u)
                v = *(const bf16x8*)(h1n + ((((size_t)n << 12) + (iy << 6) + ix) << 7) + (ck << 5) + (ci8 << 3));
            *(bf16x8*)(sm + cell * S2CP + (ci8 << 3)) = v;
        }
        __syncthreads();
        int ky = 0, kx = 0;
        for (int tap = 0; tap < 25; ++tap){
            bf16x8 a[2];
            #pragma unroll
            for (int j = 0; j < 2; ++j){
                int r = 2 * ry + ky;
                int c = 2 * ((j << 4) + lm) + kx;
                a[j] = *(const bf16x8*)(sm + (r * 67 + c) * S2CP + (lg << 3));
            }
            const ushort_t* wp = wb + ((size_t)(((tap * 4 + ck) << 7) + (ch_half << 6) + lm) << 5) + (lg << 3);
            #pragma unroll
            for (int cf = 0; cf < 4; ++cf){
                bf16x8 b = *(const bf16x8*)(wp + (cf << 9));
                acc[0][cf] = __builtin_amdgcn_mfma_f32_16x16x32_bf16(a[0], b, acc[0][cf], 0, 0, 0);
                acc[1][cf] = __builtin_amdgcn_mfma_f32_16x16x32_bf16(a[1], b, acc[1][cf], 0, 0, 0);
            }
            if (++kx == 5){ kx = 0; ++ky; }
        }
    }
    const int oy = 2 * pb + ry;
    #pragma unroll
    for (int j = 0; j < 2; ++j){
        #pragma unroll
        for (int cf = 0; cf < 4; ++cf){
            int co = (ch_half << 6) + (cf << 4) + lm;
            float b = bias[co];
            #pragma unroll
            for (int reg = 0; reg < 4; ++reg){
                int ox = (j << 4) + (lg << 2) + reg;
                int pix = (oy << 5) + ox;
                float v = fmaxf(acc[j][cf][reg] + b, 0.f);
                h2n[((((size_t)n << 10) + pix) << 7) + co] = f2bf(v);
            }
        }
    }
}

// ---------------- pregates: 5x5 SAME conv of h2 (128 ci), 256 slots, bias-init
// 4 waves = 2 px-halves x 2 slot-halves; per wave: 2 a-frags x 8 b-frags
#define GCP2 136
__global__ __launch_bounds__(256) void pregates_k(
    const ushort_t* __restrict__ in0,     // NHWC bf16 [n][1024][128]
    const ushort_t* __restrict__ wb,      // [25][4][256][32]
    const float* __restrict__ bias,
    float* __restrict__ outp)
{
    __shared__ ushort_t sm[216 * GCP2];   // 58752 B
    const int pb = blockIdx.x, n = blockIdx.y;
    const int tid = threadIdx.x, lane = tid & 63, wv = tid >> 6;
    const int fh = wv & 1, sh = wv >> 1;
    const int lm = lane & 15, lg = lane >> 4;

    for (int idx = tid; idx < 216 * 16; idx += 256){
        int cell = idx >> 4;
        int c8 = (idx & 15) << 3;
        int rr = cell / 36, cc = cell - rr * 36;
        int y = pb * 2 - 2 + rr, x = cc - 2;
        bf16x8 v = {0,0,0,0,0,0,0,0};
        if ((unsigned)y < 32u && (unsigned)x < 32u){
            int pix = (y << 5) + x;
            v = *(const bf16x8*)(in0 + (((size_t)((n << 10) + pix)) << 7) + c8);
        }
        *(bf16x8*)(sm + cell * GCP2 + c8) = v;
    }
    __syncthreads();

    f32x4v z4 = {0.f, 0.f, 0.f, 0.f};
    f32x4v acc[2][8];
    #pragma unroll
    for (int f = 0; f < 2; ++f)
        #pragma unroll
        for (int cf = 0; cf < 8; ++cf) acc[f][cf] = z4;

    int ky = 0, kx = 0;
    for (int tap = 0; tap < 25; ++tap){
        #pragma unroll
        for (int ck = 0; ck < 4; ++ck){
            bf16x8 a[2];
            #pragma unroll
            for (int f = 0; f < 2; ++f){
                int gf = (fh << 1) + f;
                int rr = (gf >> 1) + ky;
                int cc = ((gf & 1) << 4) + lm + kx;
                a[f] = *(const bf16x8*)(sm + (rr * 36 + cc) * GCP2 + (ck << 5) + (lg << 3));
            }
            const ushort_t* wp = wb + ((size_t)((((tap * 4 + ck) << 8) + (sh << 7) + lm)) << 5) + (lg << 3);
            #pragma unroll
            for (int cf = 0; cf < 8; ++cf){
                bf16x8 b = *(const bf16x8*)(wp + (cf << 9));
                acc[0][cf] = __builtin_amdgcn_mfma_f32_16x16x32_bf16(a[0], b, acc[0][cf], 0, 0, 0);
                acc[1][cf] = __builtin_amdgcn_mfma_f32_16x16x32_bf16(a[1], b, acc[1][cf], 0, 0, 0);
            }
        }
        if (++kx == 5){ kx = 0; ++ky; }
    }

    const int pxq = (pb << 6) + (fh << 5) + (lg << 2);
    #pragma unroll
    for (int f = 0; f < 2; ++f){
        int pxb = pxq + (f << 4);
        #pragma unroll
        for (int cf = 0; cf < 8; ++cf){
            int co = (sh << 7) + (cf << 4) + lm;   // slot
            int orig = (((co >> 4) & 3) << 6) | ((co >> 6) << 4) | (co & 15);
            float b = bias[orig];
            size_t o = (((size_t)n * 256 + co) << 10) + pxb;
            float4 st = {acc[f][cf][0] + b, acc[f][cf][1] + b, acc[f][cf][2] + b, acc[f][cf][3] + b};
            *(float4*)(outp + o) = st;
        }
    }
}

// ---------------- merged posterior+prior gate conv + fused LSTM
// 4 waves = 2 px-halves x 2 slot-halves; per wave: 2 a-frags x 8 b-frags per (tap,ck)
#define GCP 104
__global__ __launch_bounds__(256) void qp_gconv_k(
    const ushort_t* __restrict__ zn,
    const ushort_t* __restrict__ hq_in, const ushort_t* __restrict__ hp_in,
    const ushort_t* __restrict__ w_post, const ushort_t* __restrict__ w_prior,
    const float* __restrict__ pregates,
    const float* __restrict__ post_b, const float* __restrict__ prior_b,
    float* __restrict__ cq, float* __restrict__ cp,
    ushort_t* __restrict__ hq_out, ushort_t* __restrict__ hp_out)
{
    __shared__ ushort_t sm[216 * GCP];   // 44928 B
    const int pb = blockIdx.x, n = blockIdx.y, pr = blockIdx.z;
    const ushort_t* in1 = pr ? hp_in : hq_in;
    const ushort_t* wb  = pr ? w_prior : w_post;
    const float* initp  = pr ? (const float*)nullptr : pregates;
    const float* bias   = pr ? prior_b : post_b;
    float* cst          = pr ? cp : cq;
    ushort_t* hout      = pr ? hp_out : hq_out;

    const int tid = threadIdx.x, lane = tid & 63, wv = tid >> 6;
    const int fh = wv & 1, sh = wv >> 1;
    const int lm = lane & 15, lg = lane >> 4;

    for (int idx = tid; idx < 216 * 12; idx += 256){
        int cell = idx / 12;
        int c8 = (idx - cell * 12) << 3;
        int rr = cell / 36, cc = cell - rr * 36;
        int y = pb * 2 - 2 + rr, x = cc - 2;
        bf16x8 v = {0,0,0,0,0,0,0,0};
        if ((unsigned)y < 32u && (unsigned)x < 32u){
            int pix = (y << 5) + x;
            if (c8 < 32) v = *(const bf16x8*)(zn + (((size_t)((n << 10) + pix)) << 5) + c8);
            else         v = *(const bf16x8*)(in1 + (((size_t)((n << 10) + pix)) << 6) + (c8 - 32));
        }
        *(bf16x8*)(sm + cell * GCP + c8) = v;
    }
    __syncthreads();

    f32x4v z4 = {0.f, 0.f, 0.f, 0.f};
    f32x4v acc[2][8];
    #pragma unroll
    for (int f = 0; f < 2; ++f)
        #pragma unroll
        for (int cf = 0; cf < 8; ++cf) acc[f][cf] = z4;

    int ky = 0, kx = 0;
    for (int tap = 0; tap < 25; ++tap){
        #pragma unroll
        for (int ck = 0; ck < 3; ++ck){
            bf16x8 a[2];
            #pragma unroll
            for (int f = 0; f < 2; ++f){
                int gf = (fh << 1) + f;
                int rr = (gf >> 1) + ky;
                int cc = ((gf & 1) << 4) + lm + kx;
                a[f] = *(const bf16x8*)(sm + (rr * 36 + cc) * GCP + (ck << 5) + (lg << 3));
            }
            const ushort_t* wp = wb + ((size_t)((((tap * 3 + ck) << 8) + (sh << 7) + lm)) << 5) + (lg << 3);
            #pragma unroll
            for (int cf = 0; cf < 8; ++cf){
                bf16x8 b = *(const bf16x8*)(wp + (cf << 9));
                acc[0][cf] = __builtin_amdgcn_mfma_f32_16x16x32_bf16(a[0], b, acc[0][cf], 0, 0, 0);
                acc[1][cf] = __builtin_amdgcn_mfma_f32_16x16x32_bf16(a[1], b, acc[1][cf], 0, 0, 0);
            }
        }
        if (++kx == 5){ kx = 0; ++ky; }
    }

    // fused LSTM epilogue: slot = sh*128 + cf*16 + lm -> gate = cf&3, ch = (sh*2 + cf>>2)*16 + lm
    const int pxq = (pb << 6) + (fh << 5) + (lg << 2);
    #pragma unroll
    for (int f = 0; f < 2; ++f){
        int pxb = pxq + (f << 4);
        #pragma unroll
        for (int chhi = 0; chhi < 2; ++chhi){
            int ch = (((sh << 1) + chhi) << 4) + lm;
            f32x4v g4[4];
            #pragma unroll
            for (int g = 0; g < 4; ++g){
                if (initp){
                    int slot = (sh << 7) + (((chhi << 2) + g) << 4) + lm;
                    g4[g] = *(const f32x4v*)(initp + (((size_t)n * 256 + slot) << 10) + pxb);
                } else {
                    float b = bias[(g << 6) + ch];
                    f32x4v bb = {b, b, b, b};
                    g4[g] = bb;
                }
            }
            #pragma unroll
            for (int reg = 0; reg < 4; ++reg){
                float ig = acc[f][(chhi << 2) + 0][reg] + g4[0][reg];
                float fg = acc[f][(chhi << 2) + 1][reg] + g4[1][reg];
                float gg = acc[f][(chhi << 2) + 2][reg] + g4[2][reg];
                float og = acc[f][(chhi << 2) + 3][reg] + g4[3][reg];
                int px = pxb + reg;
                size_t o = ((((size_t)n << 10) + px) << 6) + ch;
                float cv = cst[o];
                float c2 = fsig(fg) * cv + fsig(ig) * ftanh(gg);
                cst[o] = c2;
                hout[o] = f2bf(fsig(og) * ftanh(c2));
            }
        }
    }
}

// ---------------- gauss head: 1x1 conv 128->64 on NHWC bf16 h2; z -> zs_n[0], KL
__global__ __launch_bounds__(256) void gauss_k(const ushort_t* __restrict__ h2n,
                                               const float* __restrict__ Wg,
                                               const float* __restrict__ bg,
                                               const float* __restrict__ eps0,
                                               ushort_t* __restrict__ zn,
                                               float* __restrict__ kl_out){
    __shared__ float w[64 * 128];
    int flat = blockIdx.x * 256 + threadIdx.x;     // [n][zc][pix]
    int pix = flat & 1023, zc = (flat >> 10) & 31, n = flat >> 15;
    for (int i = threadIdx.x; i < 64 * 128; i += 256) w[i] = Wg[i];
    __syncthreads();
    const ushort_t* hb = h2n + ((((size_t)n << 10) + pix) << 7);
    float amu = bg[zc], alv = bg[zc + 32];
    #pragma unroll
    for (int j = 0; j < 16; ++j){
        bf16x8 v = *(const bf16x8*)(hb + (j << 3));
        #pragma unroll
        for (int e = 0; e < 8; ++e){
            int ci = (j << 3) + e;
            float hv = bf2f((ushort_t)v[e]);
            amu = fmaf(hv, w[zc * 128 + ci], amu);
            alv = fmaf(hv, w[(zc + 32) * 128 + ci], alv);
        }
    }
    float s = softplusf(alv + 0.5f) + 1e-8f;
    float z = amu + s * eps0[flat];
    zn[((((size_t)n << 10) + pix) << 5) + zc] = f2bf(z);
    float kl = -logf(s) + 0.5f * (s * s + amu * amu) - 0.5f;
    kl_out[(size_t)flat * KSTEPS + 0] = kl;
}

// ---------------- fused postlin + priorlin + KL + z-sample
__global__ __launch_bounds__(256) void postprior_k(const ushort_t* __restrict__ hq,
                                                   const ushort_t* __restrict__ hp,
                                                   const float* __restrict__ Wq,
                                                   const float* __restrict__ bq,
                                                   const float* __restrict__ Wp,
                                                   const float* __restrict__ bp,
                                                   const float* __restrict__ eps_s,
                                                   ushort_t* __restrict__ zn_next,
                                                   float* __restrict__ kl_out, int step){
    __shared__ float wq[64 * 64];
    __shared__ float wp[64 * 64];
    int flat = blockIdx.x * 256 + threadIdx.x;     // [n][zc][pix]
    int pix = flat & 1023, zc = (flat >> 10) & 31, n = flat >> 15;
    for (int i = threadIdx.x; i < 4096; i += 256){ wq[i] = Wq[i]; wp[i] = Wp[i]; }
    __syncthreads();
    const ushort_t* hqb = hq + ((((size_t)n << 10) + pix) << 6);
    const ushort_t* hpb = hp + ((((size_t)n << 10) + pix) << 6);
    float qmu = bq[zc], qlv = bq[zc + 32], pmu = bp[zc], plv = bp[zc + 32];
    #pragma unroll
    for (int j = 0; j < 8; ++j){
        bf16x8 vq = *(const bf16x8*)(hqb + (j << 3));
        bf16x8 vp = *(const bf16x8*)(hpb + (j << 3));
        #pragma unroll
        for (int e = 0; e < 8; ++e){
            int ci = (j << 3) + e;
            float hv = bf2f((ushort_t)vq[e]);
            float pv = bf2f((ushort_t)vp[e]);
            qmu = fmaf(hv, wq[zc * 64 + ci], qmu);
            qlv = fmaf(hv, wq[(zc + 32) * 64 + ci], qlv);
            pmu = fmaf(pv, wp[zc * 64 + ci], pmu);
            plv = fmaf(pv, wp[(zc + 32) * 64 + ci], plv);
        }
    }
    float qsv = softplusf(qlv + 0.5f) + 1e-8f;
    float psv = softplusf(plv + 0.5f) + 1e-8f;
    float z = qmu + qsv * eps_s[flat];
    zn_next[((((size_t)n << 10) + pix) << 5) + zc] = f2bf(z);
    float d = qmu - pmu;
    float kl = logf(psv / qsv) + (qsv * qsv + d * d) / (2.f * psv * psv) - 0.5f;
    kl_out[(size_t)flat * KSTEPS + step] = kl;
}

// ---------------- dec1 MFMA: conv_transpose 4x4 s2 SAME, 32->128, 32x32 -> 64x64, ReLU
#define D1CP 40
__global__ __launch_bounds__(256) void dec1m_k(const ushort_t* __restrict__ zn, // [n][1024][32]
                                               const ushort_t* __restrict__ wb, // [16][128][32]
                                               const float* __restrict__ bias,
                                               ushort_t* __restrict__ out){     // [n][4096][128]
    __shared__ ushort_t sm[105 * D1CP];
    const int pb = blockIdx.x, py = blockIdx.y, n = blockIdx.z;
    const int tid = threadIdx.x, lane = tid & 63, wv = tid >> 6;
    const int pq = wv >> 1, ch = wv & 1;
    const int lm = lane & 15, lg = lane >> 4;

    for (int idx = tid; idx < 105 * 4; idx += 256){
        int ci8 = idx & 3, cell = idx >> 2;
        int r = cell / 35, c = cell - r * 35;
        int iy = 2 * pb + py - 1 + r, ix = c - 1;
        bf16x8 v = {0,0,0,0,0,0,0,0};
        if ((unsigned)iy < 32u && (unsigned)ix < 32u)
            v = *(const bf16x8*)(zn + (((size_t)((n << 10) + (iy << 5) + ix)) << 5) + (ci8 << 3));
        *(bf16x8*)(sm + cell * D1CP + (ci8 << 3)) = v;
    }
    __syncthreads();

    f32x4v z4 = {0.f, 0.f, 0.f, 0.f};
    f32x4v acc[4][4];
    #pragma unroll
    for (int f = 0; f < 4; ++f)
        #pragma unroll
        for (int cf = 0; cf < 4; ++cf) acc[f][cf] = z4;

    #pragma unroll
    for (int m = 0; m < 2; ++m){
        #pragma unroll
        for (int l = 0; l < 2; ++l){
            int tap = ((py + 2 * m) << 2) + pq + 2 * l;
            bf16x8 a[4];
            #pragma unroll
            for (int f = 0; f < 4; ++f){
                int cell = ((f >> 1) + m) * 35 + ((f & 1) << 4) + lm + pq + l;
                a[f] = *(const bf16x8*)(sm + cell * D1CP + (lg << 3));
            }
            const ushort_t* wp = wb + ((size_t)((tap << 7) + (ch << 6) + lm) << 5) + (lg << 3);
            #pragma unroll
            for (int cf = 0; cf < 4; ++cf){
                bf16x8 b = *(const bf16x8*)(wp + (cf << 9));
                #pragma unroll
                for (int f = 0; f < 4; ++f)
                    acc[f][cf] = __builtin_amdgcn_mfma_f32_16x16x32_bf16(a[f], b, acc[f][cf], 0, 0, 0);
            }
        }
    }

    #pragma unroll
    for (int f = 0; f < 4; ++f){
        #pragma unroll
        for (int cf = 0; cf < 4; ++cf){
            int co = (ch << 6) + (cf << 4) + lm;
            float b = bias[co];
            #pragma unroll
            for (int reg = 0; reg < 4; ++reg){
                int qpix = (pb << 6) + (f << 4) + (lg << 2) + reg;
                int qy = qpix >> 5, qx = qpix & 31;
                int oy = 2 * qy + py, ox = 2 * qx + pq;
                float v = fmaxf(acc[f][cf][reg] + b, 0.f);
                out[(((size_t)(n << 12) + (oy << 6) + ox) << 7) + co] = f2bf(v);
            }
        }
    }
}

// ---------------- dec2 tiled: conv_transpose 4x4 s2 SAME, 128->1, 64x64 -> 128x128
__global__ __launch_bounds__(256) void dec2t_k(const ushort_t* __restrict__ a,  // [n][4096][128]
                                               const float* __restrict__ wT,    // [16][128]
                                               const float* __restrict__ bias,
                                               float* __restrict__ out){        // [n][16384]
    __shared__ ushort_t sm[660 * 40];    // 10 rows x 66 cols x (32ci + 8 pad)
    __shared__ float ws[2048];
    const int t = blockIdx.x, n = blockIdx.y;
    const int tid = threadIdx.x;
    const int oyl = tid & 15, oxb = (tid >> 4) << 3;
    const int oy = (t << 4) + oyl;
    const int py = oy & 1;
    const int iyA = (oy - 2 + py) >> 1;
    const int rA = iyA - (t << 3) + 1;
    for (int i = tid; i < 2048; i += 256) ws[i] = wT[i];

    float acc[8];
    float b0 = bias[0];
    #pragma unroll
    for (int p = 0; p < 8; ++p) acc[p] = b0;

    for (int cc = 0; cc < 4; ++cc){
        __syncthreads();
        for (int idx = tid; idx < 2640; idx += 256){
            int q = idx & 3, cell = idx >> 2;
            int r = cell / 66, c = cell - r * 66;
            int iy = (t << 3) - 1 + r, ix = c - 1;
            bf16x8 v = {0,0,0,0,0,0,0,0};
            if ((unsigned)iy < 64u && (unsigned)ix < 64u)
                v = *(const bf16x8*)(a + ((((size_t)n << 12) + (iy << 6) + ix) << 7) + (cc << 5) + (q << 3));
            *(bf16x8*)(sm + cell * 40 + (q << 3)) = v;
        }
        __syncthreads();
        #pragma unroll
        for (int p = 0; p < 8; ++p){
            int ox = oxb + p;
            int qx = ox & 1;
            int cA = ((ox - 2 + qx) >> 1) + 1;
            #pragma unroll
            for (int m = 0; m < 2; ++m){
                #pragma unroll
                for (int l = 0; l < 2; ++l){
                    const ushort_t* sp = sm + ((rA + m) * 66 + cA + l) * 40;
                    const float* wp = ws + ((((py + 2 * m) << 2) + qx + 2 * l) << 7) + (cc << 5);
                    #pragma unroll
                    for (int j = 0; j < 4; ++j){
                        bf16x8 v = *(const bf16x8*)(sp + (j << 3));
                        #pragma unroll
                        for (int e = 0; e < 8; ++e)
                            acc[p] = fmaf(bf2f((ushort_t)v[e]), wp[(j << 3) + e], acc[p]);
                    }
                }
            }
        }
    }
    size_t o = ((size_t)n << 14) + ((size_t)oy << 7) + oxb;
    float4 o0 = {acc[0], acc[1], acc[2], acc[3]};
    float4 o1 = {acc[4], acc[5], acc[6], acc[7]};
    *reinterpret_cast<float4*>(out + o) = o0;
    *reinterpret_cast<float4*>(out + o + 4) = o1;
}

// ---------------- stick-breaking over K decoder outputs
__global__ __launch_bounds__(256) void stick_k(const float* __restrict__ dec,
                                               float* __restrict__ lm){
    int flat = blockIdx.x * 256 + threadIdx.x;
    float ss = 0.f;
    #pragma unroll
    for (int k = 0; k < KSTEPS; ++k){
        float v = dec[(size_t)k * (BATCH * 16384) + flat];
        if (k < KSTEPS - 1){
            lm[(size_t)k * (BATCH * 16384) + flat] = ss + logsigf(v);
            ss += logsigf(-v);
        } else {
            lm[(size_t)k * (BATCH * 16384) + flat] = ss + logsigf(v);
        }
    }
}

extern "C" void kernel_launch(void* const* d_in, const int* in_sizes, int n_in,
                              void* d_out, int out_size, void* d_ws, size_t ws_size,
                              hipStream_t stream){
    const float* x        = (const float*)d_in[0];
    const float* eps      = (const float*)d_in[1];
    const float* stem1_W  = (const float*)d_in[2];
    const float* stem1_b  = (const float*)d_in[3];
    const float* stem2_W  = (const float*)d_in[4];
    const float* stem2_b  = (const float*)d_in[5];
    const float* gauss_W  = (const float*)d_in[6];
    const float* gauss_b  = (const float*)d_in[7];
    const float* post_Wx  = (const float*)d_in[8];
    const float* post_Wh  = (const float*)d_in[9];
    const float* post_b   = (const float*)d_in[10];
    const float* postlin_W= (const float*)d_in[11];
    const float* postlin_b= (const float*)d_in[12];
    const float* prior_Wx = (const float*)d_in[13];
    const float* prior_Wh = (const float*)d_in[14];
    const float* prior_b  = (const float*)d_in[15];
    const float* priorlin_W=(const float*)d_in[16];
    const float* priorlin_b=(const float*)d_in[17];
    const float* dec1_W   = (const float*)d_in[18];
    const float* dec1_b   = (const float*)d_in[19];
    const float* dec2_W   = (const float*)d_in[20];
    const float* dec2_b   = (const float*)d_in[21];

    float* lm_out = (float*)d_out;
    float* kl_out = lm_out + (size_t)KSTEPS * BATCH * 16384;

    float* p = (float*)d_ws;
    ushort_t* h1n = (ushort_t*)p; p += (size_t)16777216;             // 33.5 MB bf16 [32][4096][128]; d1out alias
    float* pregates = p; p += (size_t)BATCH * 256 * 1024;            // 33.5 MB f32 slot layout
    float* dco   = p; p += (size_t)KSTEPS * BATCH * 16384;           // 12.6 MB f32
    float* cq    = p; p += (size_t)BATCH * 64 * 1024;                // zeroed
    float* cp    = p; p += (size_t)BATCH * 64 * 1024;                // zeroed
    ushort_t* hq_a = (ushort_t*)p; p += (size_t)BATCH * 64 * 1024 / 2;  // zeroed
    ushort_t* hp_a = (ushort_t*)p; p += (size_t)BATCH * 64 * 1024 / 2;  // zeroed
    ushort_t* hq_b = (ushort_t*)p; p += (size_t)BATCH * 64 * 1024 / 2;
    ushort_t* hp_b = (ushort_t*)p; p += (size_t)BATCH * 64 * 1024 / 2;
    ushort_t* zs_n = (ushort_t*)p; p += (size_t)KSTEPS * BATCH * ZDIM * 1024 / 2; // [6][32][1024][32] bf16
    ushort_t* h2_n = (ushort_t*)p; p += (size_t)BATCH * HDIM * 1024 / 2;          // [32][1024][128] bf16
    ushort_t* w_pre   = (ushort_t*)p; p += 409600;   // 25*4*256*32 = 819200 us
    ushort_t* w_post  = (ushort_t*)p; p += 307200;   // 614400 us
    ushort_t* w_prior = (ushort_t*)p; p += 307200;
    ushort_t* w_stem2 = (ushort_t*)p; p += 204800;   // 409600 us
    ushort_t* wdec1b  = (ushort_t*)p; p += 32768;    // 65536 us
    float* wstem1 = p; p += 9600;
    float* wdec2T = p; p += 2048;

    ushort_t* d1out = h1n;     // decoder phase reuse (bf16 [32][4096][128])

    // zero c_q, c_p (f32) + h_q_a, h_p_a (bf16) — contiguous
    hipMemsetAsync(cq, 0, (size_t)2097152 * 4 * 2 + (size_t)2097152 * 2 * 2, stream);

    // weight conversions
    cvtw_k<<<3200, 256, 0, stream>>>(post_Wx, w_pre, 160, 0, 4, 0, 4, 256, 1);
    cvtw_k<<<800, 256, 0, stream>>>(post_Wx, w_post, 160, 128, 1, 0, 3, 256, 1);
    cvtw_k<<<1600, 256, 0, stream>>>(post_Wh, w_post, 64, 0, 2, 1, 3, 256, 1);
    cvtw_k<<<800, 256, 0, stream>>>(prior_Wx, w_prior, 32, 0, 1, 0, 3, 256, 1);
    cvtw_k<<<1600, 256, 0, stream>>>(prior_Wh, w_prior, 64, 0, 2, 1, 3, 256, 1);
    cvtw_k<<<1600, 256, 0, stream>>>(stem2_W, w_stem2, 128, 0, 4, 0, 4, 128, 0);
    dec1wb_k<<<256, 256, 0, stream>>>(dec1_W, wdec1b);
    dec2wt_k<<<8, 256, 0, stream>>>(dec2_W, wdec2T);
    stem1wt_k<<<38, 256, 0, stream>>>(stem1_W, wstem1);

    stem1_k<<<dim3(256, 32), 256, 0, stream>>>(x, wstem1, stem1_b, h1n);
    s2m_k<<<dim3(16, 32), 256, 0, stream>>>(h1n, w_stem2, stem2_b, h2_n);
    gauss_k<<<4096, 256, 0, stream>>>(h2_n, gauss_W, gauss_b, eps, zs_n, kl_out);
    pregates_k<<<dim3(16, 32), 256, 0, stream>>>(h2_n, w_pre, post_b, pregates);

    ushort_t* hq_in = hq_a; ushort_t* hq_out = hq_b;
    ushort_t* hp_in = hp_a; ushort_t* hp_out = hp_b;
    for (int s = 0; s < KSTEPS - 1; ++s){
        const ushort_t* zn_s = zs_n + (size_t)s * 1048576;
        qp_gconv_k<<<dim3(16, 32, 2), 256, 0, stream>>>(
            zn_s, hq_in, hp_in, w_post, w_prior, pregates, post_b, prior_b,
            cq, cp, hq_out, hp_out);
        postprior_k<<<4096, 256, 0, stream>>>(hq_out, hp_out,
            postlin_W, postlin_b, priorlin_W, priorlin_b,
            eps + (size_t)(s + 1) * 1048576,
            zs_n + (size_t)(s + 1) * 1048576, kl_out, s + 1);
        ushort_t* t;
        t = hq_in; hq_in = hq_out; hq_out = t;
        t = hp_in; hp_in = hp_out; hp_out = t;
    }

    for (int k = 0; k < KSTEPS; ++k){
        dec1m_k<<<dim3(16, 2, 32), 256, 0, stream>>>(zs_n + (size_t)k * 1048576, wdec1b, dec1_b, d1out);
        dec2t_k<<<dim3(8, 32), 256, 0, stream>>>(d1out, wdec2T, dec2_b, dco + (size_t)k * BATCH * 16384);
    }
    stick_k<<<2048, 256, 0, stream>>>(dco, lm_out);
}

// Round 9
// 1626.048 us; speedup vs baseline: 1.4267x; 1.4267x over previous
//
#include <hip/hip_runtime.h>
#include <math.h>

#define BATCH 32
#define HDIM 128
#define ZDIM 32
#define KSTEPS 6

typedef unsigned short ushort_t;
using bf16x8 = __attribute__((ext_vector_type(8))) short;
using f32x4v = __attribute__((ext_vector_type(4))) float;

__device__ __forceinline__ float softplusf(float x){
    return fmaxf(x, 0.f) + log1pf(expf(-fabsf(x)));
}
__device__ __forceinline__ float logsigf(float x){
    return fminf(x, 0.f) - log1pf(expf(-fabsf(x)));
}
__device__ __forceinline__ float fsig(float x){
    return __builtin_amdgcn_rcpf(1.f + __expf(-x));
}
__device__ __forceinline__ float ftanh(float x){
    x = fminf(fmaxf(x, -15.f), 15.f);
    float e = __expf(2.f * x);
    return (e - 1.f) * __builtin_amdgcn_rcpf(e + 1.f);
}
__device__ __forceinline__ float bf2f(ushort_t u){
    return __uint_as_float(((unsigned)u) << 16);
}
__device__ __forceinline__ ushort_t f2bf(float f){
    unsigned x = __float_as_uint(f);
    unsigned r = (x + 0x7fffu + ((x >> 16) & 1u)) >> 16;
    return (ushort_t)r;
}

// ---------------- weight prep kernels ----------------
__global__ __launch_bounds__(256) void stem1wt_k(const float* __restrict__ W,
                                                 float* __restrict__ Wo){
    int idx = blockIdx.x * 256 + threadIdx.x;   // 9600
    if (idx >= 9600) return;
    int co = idx & 127, tap = idx >> 7;
    Wo[(tap << 7) + co] = W[co * 75 + tap];
}

// OIHW f32 -> [tap][ck][coN][ci32] bf16 (opt. gate-slot permute on co)
__global__ __launch_bounds__(256) void cvtw_k(const float* __restrict__ src,
                                              ushort_t* __restrict__ dst,
                                              int Cfull, int ci_off, int ncs,
                                              int ck_off, int NCHK, int NCO, int permute){
    int idx = blockIdx.x * 256 + threadIdx.x;
    int total = 25 * ncs * NCO * 32;
    if (idx >= total) return;
    int per_tap = ncs * NCO * 32;
    int tap = idx / per_tap;
    int r = idx - tap * per_tap;
    int ckl = r / (NCO * 32);
    int r2 = r - ckl * (NCO * 32);
    int co = r2 >> 5, cl = r2 & 31;
    int s = permute ? ((((co & 63) >> 4) << 6) | ((co >> 6) << 4) | (co & 15)) : co;
    float v = src[((size_t)co * Cfull + ci_off + (ckl << 5) + cl) * 25 + tap];
    dst[(((size_t)(tap * NCHK + ck_off + ckl)) * NCO + s) * 32 + cl] = f2bf(v);
}

// dec1_W [co128][ci32][tap16] f32 -> [tap16][co128][ci32] bf16
__global__ __launch_bounds__(256) void dec1wb_k(const float* __restrict__ W,
                                                ushort_t* __restrict__ Wo){
    int idx = blockIdx.x * 256 + threadIdx.x;      // 65536
    int ci = idx & 31, co = (idx >> 5) & 127, tap = idx >> 12;
    Wo[idx] = f2bf(W[(((co << 5) + ci) << 4) + tap]);
}

// dec2_W [ci128][tap16] f32 -> [tap16][ci128] f32
__global__ __launch_bounds__(256) void dec2wt_k(const float* __restrict__ W,
                                                float* __restrict__ Wo){
    int idx = blockIdx.x * 256 + threadIdx.x;      // 2048
    if (idx >= 2048) return;
    int ci = idx & 127, tap = idx >> 7;
    Wo[idx] = W[(ci << 4) + tap];
}

// ---------------- stem1: conv 5x5 s2, 3->128, 128x128 -> 64x64, ReLU, out NHWC bf16
__global__ __launch_bounds__(256) void stem1_k(const float* __restrict__ x,
                                               const float* __restrict__ WtT, // [tap75][co128]
                                               const float* __restrict__ bias,
                                               ushort_t* __restrict__ h1n){
    __shared__ float ws[75 * 128];
    __shared__ float xs[3][5][36];
    const int n = blockIdx.y, pb = blockIdx.x;
    const int oy = pb >> 2, oxb = (pb & 3) << 4;
    const int tid = threadIdx.x;
    const int co = tid & 127, ps = tid >> 7;
    for (int i = tid; i < 9600; i += 256) ws[i] = WtT[i];
    for (int idx = tid; idx < 525; idx += 256){
        int ci = idx / 175, r = (idx - ci * 175) / 35, c = idx - ci * 175 - r * 35;
        int iy = 2 * oy - 1 + r, ix = 2 * oxb - 1 + c;
        float v = 0.f;
        if ((unsigned)iy < 128u && (unsigned)ix < 128u)
            v = x[(size_t)n * 49152 + (ci << 14) + (iy << 7) + ix];
        xs[ci][r][c] = v;
    }
    __syncthreads();
    float b = bias[co];
    float acc[8];
    #pragma unroll
    for (int t = 0; t < 8; ++t) acc[t] = b;
    #pragma unroll
    for (int ci = 0; ci < 3; ++ci){
        #pragma unroll
        for (int ky = 0; ky < 5; ++ky){
            const float* row = &xs[ci][ky][0];
            #pragma unroll
            for (int kx = 0; kx < 5; ++kx){
                float wv = ws[((ci * 25 + ky * 5 + kx) << 7) + co];
                #pragma unroll
                for (int t = 0; t < 8; ++t)
                    acc[t] = fmaf(row[4 * t + 2 * ps + kx], wv, acc[t]);
            }
        }
    }
    #pragma unroll
    for (int t = 0; t < 8; ++t){
        int pix = (oy << 6) + oxb + (t << 1) + ps;
        h1n[((((size_t)n << 12) + pix) << 7) + co] = f2bf(fmaxf(acc[t], 0.f));
    }
}

// ---------------- stem2 MFMA: conv 5x5 s2 SAME, 128->128, 64x64 -> 32x32, ReLU, out bf16
#define S2CP 40
__global__ __launch_bounds__(256) void s2m_k(const ushort_t* __restrict__ h1n,
                                             const ushort_t* __restrict__ wb, // [25][4][128][32]
                                             const float* __restrict__ bias,
                                             ushort_t* __restrict__ h2n){
    __shared__ ushort_t sm[7 * 67 * S2CP];
    const int pb = blockIdx.x, n = blockIdx.y;
    const int tid = threadIdx.x, lane = tid & 63, wv = tid >> 6;
    const int ry = wv >> 1, ch_half = wv & 1;
    const int lm = lane & 15, lg = lane >> 4;

    f32x4v z4 = {0.f, 0.f, 0.f, 0.f};
    f32x4v acc[2][4];
    #pragma unroll
    for (int j = 0; j < 2; ++j)
        #pragma unroll
        for (int cf = 0; cf < 4; ++cf) acc[j][cf] = z4;

    for (int ck = 0; ck < 4; ++ck){
        __syncthreads();
        for (int idx = tid; idx < 7 * 67 * 4; idx += 256){
            int ci8 = idx & 3, cell = idx >> 2;
            int r = cell / 67, c = cell - r * 67;
            int iy = (pb << 2) - 1 + r, ix = c - 1;
            bf16x8 v = {0,0,0,0,0,0,0,0};
            if ((unsigned)iy < 64u && (unsigned)ix < 64u)
                v = *(const bf16x8*)(h1n + ((((size_t)n << 12) + (iy << 6) + ix) << 7) + (ck << 5) + (ci8 << 3));
            *(bf16x8*)(sm + cell * S2CP + (ci8 << 3)) = v;
        }
        __syncthreads();
        int ky = 0, kx = 0;
        for (int tap = 0; tap < 25; ++tap){
            bf16x8 a[2];
            #pragma unroll
            for (int j = 0; j < 2; ++j){
                int r = 2 * ry + ky;
                int c = 2 * ((j << 4) + lm) + kx;
                a[j] = *(const bf16x8*)(sm + (r * 67 + c) * S2CP + (lg << 3));
            }
            const ushort_t* wp = wb + ((size_t)(((tap * 4 + ck) << 7) + (ch_half << 6) + lm) << 5) + (lg << 3);
            #pragma unroll
            for (int cf = 0; cf < 4; ++cf){
                bf16x8 b = *(const bf16x8*)(wp + (cf << 9));
                acc[0][cf] = __builtin_amdgcn_mfma_f32_16x16x32_bf16(a[0], b, acc[0][cf], 0, 0, 0);
                acc[1][cf] = __builtin_amdgcn_mfma_f32_16x16x32_bf16(a[1], b, acc[1][cf], 0, 0, 0);
            }
            if (++kx == 5){ kx = 0; ++ky; }
        }
    }
    const int oy = 2 * pb + ry;
    #pragma unroll
    for (int j = 0; j < 2; ++j){
        #pragma unroll
        for (int cf = 0; cf < 4; ++cf){
            int co = (ch_half << 6) + (cf << 4) + lm;
            float b = bias[co];
            #pragma unroll
            for (int reg = 0; reg < 4; ++reg){
                int ox = (j << 4) + (lg << 2) + reg;
                int pix = (oy << 5) + ox;
                float v = fmaxf(acc[j][cf][reg] + b, 0.f);
                h2n[((((size_t)n << 10) + pix) << 7) + co] = f2bf(v);
            }
        }
    }
}

// ---------------- pregates: 5x5 SAME conv of h2 (128 ci), 256 slots, bias-init
// 4-row tile (128 px), 4 waves x 64 slots, b-prefetch. grid (8, 32)
#define GCP2 136
__global__ __launch_bounds__(256) void pregates_k(
    const ushort_t* __restrict__ in0,     // NHWC bf16 [n][1024][128]
    const ushort_t* __restrict__ wb,      // [100][256][32]
    const float* __restrict__ bias,
    float* __restrict__ outp)
{
    __shared__ ushort_t sm[288 * GCP2];   // 78,336 B
    const int pb = blockIdx.x, n = blockIdx.y;
    const int tid = threadIdx.x, lane = tid & 63, wv = tid >> 6;
    const int wbase = wv << 6;
    const int lm = lane & 15, lg = lane >> 4;

    for (int idx = tid; idx < 288 * 16; idx += 256){
        int cell = idx >> 4;
        int c8 = (idx & 15) << 3;
        int rr = cell / 36, cc = cell - rr * 36;
        int y = (pb << 2) - 2 + rr, x = cc - 2;
        bf16x8 v = {0,0,0,0,0,0,0,0};
        if ((unsigned)y < 32u && (unsigned)x < 32u){
            int pix = (y << 5) + x;
            v = *(const bf16x8*)(in0 + (((size_t)((n << 10) + pix)) << 7) + c8);
        }
        *(bf16x8*)(sm + cell * GCP2 + c8) = v;
    }
    __syncthreads();

    f32x4v z4 = {0.f, 0.f, 0.f, 0.f};
    f32x4v acc[8][4];
    #pragma unroll
    for (int f = 0; f < 8; ++f)
        #pragma unroll
        for (int cf = 0; cf < 4; ++cf) acc[f][cf] = z4;

    const ushort_t* wlane = wb + ((size_t)(wbase + lm) << 5) + (lg << 3);
    bf16x8 bc[4];
    #pragma unroll
    for (int cf = 0; cf < 4; ++cf) bc[cf] = *(const bf16x8*)(wlane + (cf << 9));

    int ky = 0, kx = 0, ck = 0;
    for (int it = 0; it < 100; ++it){
        int nit = it < 99 ? it + 1 : 99;
        bf16x8 bn[4];
        const ushort_t* wp = wlane + ((size_t)nit << 13);
        #pragma unroll
        for (int cf = 0; cf < 4; ++cf) bn[cf] = *(const bf16x8*)(wp + (cf << 9));
        bf16x8 a[8];
        #pragma unroll
        for (int f = 0; f < 8; ++f){
            int rr = (f >> 1) + ky;
            int cc = ((f & 1) << 4) + lm + kx;
            a[f] = *(const bf16x8*)(sm + (rr * 36 + cc) * GCP2 + (ck << 5) + (lg << 3));
        }
        #pragma unroll
        for (int cf = 0; cf < 4; ++cf)
            #pragma unroll
            for (int f = 0; f < 8; ++f)
                acc[f][cf] = __builtin_amdgcn_mfma_f32_16x16x32_bf16(a[f], bc[cf], acc[f][cf], 0, 0, 0);
        #pragma unroll
        for (int cf = 0; cf < 4; ++cf) bc[cf] = bn[cf];
        if (++ck == 4){ ck = 0; if (++kx == 5){ kx = 0; ++ky; } }
    }

    #pragma unroll
    for (int f = 0; f < 8; ++f){
        int pixb = (((pb << 2) + (f >> 1)) << 5) + ((f & 1) << 4) + (lg << 2);
        #pragma unroll
        for (int cf = 0; cf < 4; ++cf){
            int co = wbase + (cf << 4) + lm;   // slot
            int orig = (((co >> 4) & 3) << 6) | ((co >> 6) << 4) | (co & 15);
            float b = bias[orig];
            size_t o = (((size_t)n * 256 + co) << 10) + pixb;
            float4 st = {acc[f][cf][0] + b, acc[f][cf][1] + b, acc[f][cf][2] + b, acc[f][cf][3] + b};
            *(float4*)(outp + o) = st;
        }
    }
}

// ---------------- merged posterior+prior gate conv + fused LSTM
// 4-row tile (128 px), 4 waves x 64 slots, b-prefetch. grid (8, 32, 2)
#define GCP 104
__global__ __launch_bounds__(256) void qp_gconv_k(
    const ushort_t* __restrict__ zn,
    const ushort_t* __restrict__ hq_in, const ushort_t* __restrict__ hp_in,
    const ushort_t* __restrict__ w_post, const ushort_t* __restrict__ w_prior,
    const float* __restrict__ pregates,
    const float* __restrict__ post_b, const float* __restrict__ prior_b,
    float* __restrict__ cq, float* __restrict__ cp,
    ushort_t* __restrict__ hq_out, ushort_t* __restrict__ hp_out)
{
    __shared__ ushort_t sm[288 * GCP];   // 59,904 B
    const int pb = blockIdx.x, n = blockIdx.y, pr = blockIdx.z;
    const ushort_t* in1 = pr ? hp_in : hq_in;
    const ushort_t* wb  = pr ? w_prior : w_post;
    const float* initp  = pr ? (const float*)nullptr : pregates;
    const float* bias   = pr ? prior_b : post_b;
    float* cst          = pr ? cp : cq;
    ushort_t* hout      = pr ? hp_out : hq_out;

    const int tid = threadIdx.x, lane = tid & 63, wv = tid >> 6;
    const int wbase = wv << 6;
    const int lm = lane & 15, lg = lane >> 4;

    for (int idx = tid; idx < 288 * 12; idx += 256){
        int cell = idx / 12;
        int c8 = (idx - cell * 12) << 3;
        int rr = cell / 36, cc = cell - rr * 36;
        int y = (pb << 2) - 2 + rr, x = cc - 2;
        bf16x8 v = {0,0,0,0,0,0,0,0};
        if ((unsigned)y < 32u && (unsigned)x < 32u){
            int pix = (y << 5) + x;
            if (c8 < 32) v = *(const bf16x8*)(zn + (((size_t)((n << 10) + pix)) << 5) + c8);
            else         v = *(const bf16x8*)(in1 + (((size_t)((n << 10) + pix)) << 6) + (c8 - 32));
        }
        *(bf16x8*)(sm + cell * GCP + c8) = v;
    }
    __syncthreads();

    f32x4v z4 = {0.f, 0.f, 0.f, 0.f};
    f32x4v acc[8][4];
    #pragma unroll
    for (int f = 0; f < 8; ++f)
        #pragma unroll
        for (int cf = 0; cf < 4; ++cf) acc[f][cf] = z4;

    const ushort_t* wlane = wb + ((size_t)(wbase + lm) << 5) + (lg << 3);
    bf16x8 bc[4];
    #pragma unroll
    for (int cf = 0; cf < 4; ++cf) bc[cf] = *(const bf16x8*)(wlane + (cf << 9));

    int ky = 0, kx = 0, ck = 0;
    for (int it = 0; it < 75; ++it){
        int nit = it < 74 ? it + 1 : 74;
        bf16x8 bn[4];
        const ushort_t* wp = wlane + ((size_t)nit << 13);
        #pragma unroll
        for (int cf = 0; cf < 4; ++cf) bn[cf] = *(const bf16x8*)(wp + (cf << 9));
        bf16x8 a[8];
        #pragma unroll
        for (int f = 0; f < 8; ++f){
            int rr = (f >> 1) + ky;
            int cc = ((f & 1) << 4) + lm + kx;
            a[f] = *(const bf16x8*)(sm + (rr * 36 + cc) * GCP + (ck << 5) + (lg << 3));
        }
        #pragma unroll
        for (int cf = 0; cf < 4; ++cf)
            #pragma unroll
            for (int f = 0; f < 8; ++f)
                acc[f][cf] = __builtin_amdgcn_mfma_f32_16x16x32_bf16(a[f], bc[cf], acc[f][cf], 0, 0, 0);
        #pragma unroll
        for (int cf = 0; cf < 4; ++cf) bc[cf] = bn[cf];
        if (++ck == 3){ ck = 0; if (++kx == 5){ kx = 0; ++ky; } }
    }

    // fused LSTM epilogue: cf = gate (i,f,g,o), channel = wv*16+lm
    const int ch = (wv << 4) + lm;
    #pragma unroll
    for (int f = 0; f < 8; ++f){
        int pixb = (((pb << 2) + (f >> 1)) << 5) + ((f & 1) << 4) + (lg << 2);
        f32x4v g4[4];
        #pragma unroll
        for (int g = 0; g < 4; ++g){
            if (initp){
                int slot = wbase + (g << 4) + lm;
                g4[g] = *(const f32x4v*)(initp + (((size_t)n * 256 + slot) << 10) + pixb);
            } else {
                float b = bias[(g << 6) + ch];
                f32x4v bb = {b, b, b, b};
                g4[g] = bb;
            }
        }
        #pragma unroll
        for (int reg = 0; reg < 4; ++reg){
            float ig = acc[f][0][reg] + g4[0][reg];
            float fg = acc[f][1][reg] + g4[1][reg];
            float gg = acc[f][2][reg] + g4[2][reg];
            float og = acc[f][3][reg] + g4[3][reg];
            int pix = pixb + reg;
            size_t o = ((((size_t)n << 10) + pix) << 6) + ch;
            float cv = cst[o];
            float c2 = fsig(fg) * cv + fsig(ig) * ftanh(gg);
            cst[o] = c2;
            hout[o] = f2bf(fsig(og) * ftanh(c2));
        }
    }
}

// ---------------- gauss head: 1x1 conv 128->64 on NHWC bf16 h2; z -> zs_n[0], KL
__global__ __launch_bounds__(256) void gauss_k(const ushort_t* __restrict__ h2n,
                                               const float* __restrict__ Wg,
                                               const float* __restrict__ bg,
                                               const float* __restrict__ eps0,
                                               ushort_t* __restrict__ zn,
                                               float* __restrict__ kl_out){
    __shared__ float w[64 * 128];
    int flat = blockIdx.x * 256 + threadIdx.x;     // [n][zc][pix]
    int pix = flat & 1023, zc = (flat >> 10) & 31, n = flat >> 15;
    for (int i = threadIdx.x; i < 64 * 128; i += 256) w[i] = Wg[i];
    __syncthreads();
    const ushort_t* hb = h2n + ((((size_t)n << 10) + pix) << 7);
    float amu = bg[zc], alv = bg[zc + 32];
    #pragma unroll
    for (int j = 0; j < 16; ++j){
        bf16x8 v = *(const bf16x8*)(hb + (j << 3));
        #pragma unroll
        for (int e = 0; e < 8; ++e){
            int ci = (j << 3) + e;
            float hv = bf2f((ushort_t)v[e]);
            amu = fmaf(hv, w[zc * 128 + ci], amu);
            alv = fmaf(hv, w[(zc + 32) * 128 + ci], alv);
        }
    }
    float s = softplusf(alv + 0.5f) + 1e-8f;
    float z = amu + s * eps0[flat];
    zn[((((size_t)n << 10) + pix) << 5) + zc] = f2bf(z);
    float kl = -logf(s) + 0.5f * (s * s + amu * amu) - 0.5f;
    kl_out[(size_t)flat * KSTEPS + 0] = kl;
}

// ---------------- fused postlin + priorlin + KL + z-sample
__global__ __launch_bounds__(256) void postprior_k(const ushort_t* __restrict__ hq,
                                                   const ushort_t* __restrict__ hp,
                                                   const float* __restrict__ Wq,
                                                   const float* __restrict__ bq,
                                                   const float* __restrict__ Wp,
                                                   const float* __restrict__ bp,
                                                   const float* __restrict__ eps_s,
                                                   ushort_t* __restrict__ zn_next,
                                                   float* __restrict__ kl_out, int step){
    __shared__ float wq[64 * 64];
    __shared__ float wp[64 * 64];
    int flat = blockIdx.x * 256 + threadIdx.x;     // [n][zc][pix]
    int pix = flat & 1023, zc = (flat >> 10) & 31, n = flat >> 15;
    for (int i = threadIdx.x; i < 4096; i += 256){ wq[i] = Wq[i]; wp[i] = Wp[i]; }
    __syncthreads();
    const ushort_t* hqb = hq + ((((size_t)n << 10) + pix) << 6);
    const ushort_t* hpb = hp + ((((size_t)n << 10) + pix) << 6);
    float qmu = bq[zc], qlv = bq[zc + 32], pmu = bp[zc], plv = bp[zc + 32];
    #pragma unroll
    for (int j = 0; j < 8; ++j){
        bf16x8 vq = *(const bf16x8*)(hqb + (j << 3));
        bf16x8 vp = *(const bf16x8*)(hpb + (j << 3));
        #pragma unroll
        for (int e = 0; e < 8; ++e){
            int ci = (j << 3) + e;
            float hv = bf2f((ushort_t)vq[e]);
            float pv = bf2f((ushort_t)vp[e]);
            qmu = fmaf(hv, wq[zc * 64 + ci], qmu);
            qlv = fmaf(hv, wq[(zc + 32) * 64 + ci], qlv);
            pmu = fmaf(pv, wp[zc * 64 + ci], pmu);
            plv = fmaf(pv, wp[(zc + 32) * 64 + ci], plv);
        }
    }
    float qsv = softplusf(qlv + 0.5f) + 1e-8f;
    float psv = softplusf(plv + 0.5f) + 1e-8f;
    float z = qmu + qsv * eps_s[flat];
    zn_next[((((size_t)n << 10) + pix) << 5) + zc] = f2bf(z);
    float d = qmu - pmu;
    float kl = logf(psv / qsv) + (qsv * qsv + d * d) / (2.f * psv * psv) - 0.5f;
    kl_out[(size_t)flat * KSTEPS + step] = kl;
}

// ---------------- dec1 MFMA: conv_transpose 4x4 s2 SAME, 32->128, 32x32 -> 64x64, ReLU
#define D1CP 40
__global__ __launch_bounds__(256) void dec1m_k(const ushort_t* __restrict__ zn, // [n][1024][32]
                                               const ushort_t* __restrict__ wb, // [16][128][32]
                                               const float* __restrict__ bias,
                                               ushort_t* __restrict__ out){     // [n][4096][128]
    __shared__ ushort_t sm[105 * D1CP];
    const int pb = blockIdx.x, py = blockIdx.y, n = blockIdx.z;
    const int tid = threadIdx.x, lane = tid & 63, wv = tid >> 6;
    const int pq = wv >> 1, ch = wv & 1;
    const int lm = lane & 15, lg = lane >> 4;

    for (int idx = tid; idx < 105 * 4; idx += 256){
        int ci8 = idx & 3, cell = idx >> 2;
        int r = cell / 35, c = cell - r * 35;
        int iy = 2 * pb + py - 1 + r, ix = c - 1;
        bf16x8 v = {0,0,0,0,0,0,0,0};
        if ((unsigned)iy < 32u && (unsigned)ix < 32u)
            v = *(const bf16x8*)(zn + (((size_t)((n << 10) + (iy << 5) + ix)) << 5) + (ci8 << 3));
        *(bf16x8*)(sm + cell * D1CP + (ci8 << 3)) = v;
    }
    __syncthreads();

    f32x4v z4 = {0.f, 0.f, 0.f, 0.f};
    f32x4v acc[4][4];
    #pragma unroll
    for (int f = 0; f < 4; ++f)
        #pragma unroll
        for (int cf = 0; cf < 4; ++cf) acc[f][cf] = z4;

    #pragma unroll
    for (int m = 0; m < 2; ++m){
        #pragma unroll
        for (int l = 0; l < 2; ++l){
            int tap = ((py + 2 * m) << 2) + pq + 2 * l;
            bf16x8 a[4];
            #pragma unroll
            for (int f = 0; f < 4; ++f){
                int cell = ((f >> 1) + m) * 35 + ((f & 1) << 4) + lm + pq + l;
                a[f] = *(const bf16x8*)(sm + cell * D1CP + (lg << 3));
            }
            const ushort_t* wp = wb + ((size_t)((tap << 7) + (ch << 6) + lm) << 5) + (lg << 3);
            #pragma unroll
            for (int cf = 0; cf < 4; ++cf){
                bf16x8 b = *(const bf16x8*)(wp + (cf << 9));
                #pragma unroll
                for (int f = 0; f < 4; ++f)
                    acc[f][cf] = __builtin_amdgcn_mfma_f32_16x16x32_bf16(a[f], b, acc[f][cf], 0, 0, 0);
            }
        }
    }

    #pragma unroll
    for (int f = 0; f < 4; ++f){
        #pragma unroll
        for (int cf = 0; cf < 4; ++cf){
            int co = (ch << 6) + (cf << 4) + lm;
            float b = bias[co];
            #pragma unroll
            for (int reg = 0; reg < 4; ++reg){
                int qpix = (pb << 6) + (f << 4) + (lg << 2) + reg;
                int qy = qpix >> 5, qx = qpix & 31;
                int oy = 2 * qy + py, ox = 2 * qx + pq;
                float v = fmaxf(acc[f][cf][reg] + b, 0.f);
                out[(((size_t)(n << 12) + (oy << 6) + ox) << 7) + co] = f2bf(v);
            }
        }
    }
}

// ---------------- dec2 tiled: conv_transpose 4x4 s2 SAME, 128->1, 64x64 -> 128x128
__global__ __launch_bounds__(256) void dec2t_k(const ushort_t* __restrict__ a,  // [n][4096][128]
                                               const float* __restrict__ wT,    // [16][128]
                                               const float* __restrict__ bias,
                                               float* __restrict__ out){        // [n][16384]
    __shared__ ushort_t sm[660 * 40];    // 10 rows x 66 cols x (32ci + 8 pad)
    __shared__ float ws[2048];
    const int t = blockIdx.x, n = blockIdx.y;
    const int tid = threadIdx.x;
    const int oyl = tid & 15, oxb = (tid >> 4) << 3;
    const int oy = (t << 4) + oyl;
    const int py = oy & 1;
    const int iyA = (oy - 2 + py) >> 1;
    const int rA = iyA - (t << 3) + 1;
    for (int i = tid; i < 2048; i += 256) ws[i] = wT[i];

    float acc[8];
    float b0 = bias[0];
    #pragma unroll
    for (int p = 0; p < 8; ++p) acc[p] = b0;

    for (int cc = 0; cc < 4; ++cc){
        __syncthreads();
        for (int idx = tid; idx < 2640; idx += 256){
            int q = idx & 3, cell = idx >> 2;
            int r = cell / 66, c = cell - r * 66;
            int iy = (t << 3) - 1 + r, ix = c - 1;
            bf16x8 v = {0,0,0,0,0,0,0,0};
            if ((unsigned)iy < 64u && (unsigned)ix < 64u)
                v = *(const bf16x8*)(a + ((((size_t)n << 12) + (iy << 6) + ix) << 7) + (cc << 5) + (q << 3));
            *(bf16x8*)(sm + cell * 40 + (q << 3)) = v;
        }
        __syncthreads();
        #pragma unroll
        for (int p = 0; p < 8; ++p){
            int ox = oxb + p;
            int qx = ox & 1;
            int cA = ((ox - 2 + qx) >> 1) + 1;
            #pragma unroll
            for (int m = 0; m < 2; ++m){
                #pragma unroll
                for (int l = 0; l < 2; ++l){
                    const ushort_t* sp = sm + ((rA + m) * 66 + cA + l) * 40;
                    const float* wp = ws + ((((py + 2 * m) << 2) + qx + 2 * l) << 7) + (cc << 5);
                    #pragma unroll
                    for (int j = 0; j < 4; ++j){
                        bf16x8 v = *(const bf16x8*)(sp + (j << 3));
                        #pragma unroll
                        for (int e = 0; e < 8; ++e)
                            acc[p] = fmaf(bf2f((ushort_t)v[e]), wp[(j << 3) + e], acc[p]);
                    }
                }
            }
        }
    }
    size_t o = ((size_t)n << 14) + ((size_t)oy << 7) + oxb;
    float4 o0 = {acc[0], acc[1], acc[2], acc[3]};
    float4 o1 = {acc[4], acc[5], acc[6], acc[7]};
    *reinterpret_cast<float4*>(out + o) = o0;
    *reinterpret_cast<float4*>(out + o + 4) = o1;
}

// ---------------- stick-breaking over K decoder outputs
__global__ __launch_bounds__(256) void stick_k(const float* __restrict__ dec,
                                               float* __restrict__ lm){
    int flat = blockIdx.x * 256 + threadIdx.x;
    float ss = 0.f;
    #pragma unroll
    for (int k = 0; k < KSTEPS; ++k){
        float v = dec[(size_t)k * (BATCH * 16384) + flat];
        if (k < KSTEPS - 1){
            lm[(size_t)k * (BATCH * 16384) + flat] = ss + logsigf(v);
            ss += logsigf(-v);
        } else {
            lm[(size_t)k * (BATCH * 16384) + flat] = ss + logsigf(v);
        }
    }
}

extern "C" void kernel_launch(void* const* d_in, const int* in_sizes, int n_in,
                              void* d_out, int out_size, void* d_ws, size_t ws_size,
                              hipStream_t stream){
    const float* x        = (const float*)d_in[0];
    const float* eps      = (const float*)d_in[1];
    const float* stem1_W  = (const float*)d_in[2];
    const float* stem1_b  = (const float*)d_in[3];
    const float* stem2_W  = (const float*)d_in[4];
    const float* stem2_b  = (const float*)d_in[5];
    const float* gauss_W  = (const float*)d_in[6];
    const float* gauss_b  = (const float*)d_in[7];
    const float* post_Wx  = (const float*)d_in[8];
    const float* post_Wh  = (const float*)d_in[9];
    const float* post_b   = (const float*)d_in[10];
    const float* postlin_W= (const float*)d_in[11];
    const float* postlin_b= (const float*)d_in[12];
    const float* prior_Wx = (const float*)d_in[13];
    const float* prior_Wh = (const float*)d_in[14];
    const float* prior_b  = (const float*)d_in[15];
    const float* priorlin_W=(const float*)d_in[16];
    const float* priorlin_b=(const float*)d_in[17];
    const float* dec1_W   = (const float*)d_in[18];
    const float* dec1_b   = (const float*)d_in[19];
    const float* dec2_W   = (const float*)d_in[20];
    const float* dec2_b   = (const float*)d_in[21];

    float* lm_out = (float*)d_out;
    float* kl_out = lm_out + (size_t)KSTEPS * BATCH * 16384;

    float* p = (float*)d_ws;
    ushort_t* h1n = (ushort_t*)p; p += (size_t)16777216;             // 33.5 MB bf16 [32][4096][128]; d1out alias
    float* pregates = p; p += (size_t)BATCH * 256 * 1024;            // 33.5 MB f32 slot layout
    float* dco   = p; p += (size_t)KSTEPS * BATCH * 16384;           // 12.6 MB f32
    float* cq    = p; p += (size_t)BATCH * 64 * 1024;                // zeroed
    float* cp    = p; p += (size_t)BATCH * 64 * 1024;                // zeroed
    ushort_t* hq_a = (ushort_t*)p; p += (size_t)BATCH * 64 * 1024 / 2;  // zeroed
    ushort_t* hp_a = (ushort_t*)p; p += (size_t)BATCH * 64 * 1024 / 2;  // zeroed
    ushort_t* hq_b = (ushort_t*)p; p += (size_t)BATCH * 64 * 1024 / 2;
    ushort_t* hp_b = (ushort_t*)p; p += (size_t)BATCH * 64 * 1024 / 2;
    ushort_t* zs_n = (ushort_t*)p; p += (size_t)KSTEPS * BATCH * ZDIM * 1024 / 2; // [6][32][1024][32] bf16
    ushort_t* h2_n = (ushort_t*)p; p += (size_t)BATCH * HDIM * 1024 / 2;          // [32][1024][128] bf16
    ushort_t* w_pre   = (ushort_t*)p; p += 409600;   // 100*256*32 = 819200 us
    ushort_t* w_post  = (ushort_t*)p; p += 307200;   // 75*256*32 = 614400 us
    ushort_t* w_prior = (ushort_t*)p; p += 307200;
    ushort_t* w_stem2 = (ushort_t*)p; p += 204800;   // 409600 us
    ushort_t* wdec1b  = (ushort_t*)p; p += 32768;    // 65536 us
    float* wstem1 = p; p += 9600;
    float* wdec2T = p; p += 2048;

    ushort_t* d1out = h1n;     // decoder phase reuse (bf16 [32][4096][128])

    // zero c_q, c_p (f32) + h_q_a, h_p_a (bf16) — contiguous
    hipMemsetAsync(cq, 0, (size_t)2097152 * 4 * 2 + (size_t)2097152 * 2 * 2, stream);

    // weight conversions
    cvtw_k<<<3200, 256, 0, stream>>>(post_Wx, w_pre, 160, 0, 4, 0, 4, 256, 1);
    cvtw_k<<<800, 256, 0, stream>>>(post_Wx, w_post, 160, 128, 1, 0, 3, 256, 1);
    cvtw_k<<<1600, 256, 0, stream>>>(post_Wh, w_post, 64, 0, 2, 1, 3, 256, 1);
    cvtw_k<<<800, 256, 0, stream>>>(prior_Wx, w_prior, 32, 0, 1, 0, 3, 256, 1);
    cvtw_k<<<1600, 256, 0, stream>>>(prior_Wh, w_prior, 64, 0, 2, 1, 3, 256, 1);
    cvtw_k<<<1600, 256, 0, stream>>>(stem2_W, w_stem2, 128, 0, 4, 0, 4, 128, 0);
    dec1wb_k<<<256, 256, 0, stream>>>(dec1_W, wdec1b);
    dec2wt_k<<<8, 256, 0, stream>>>(dec2_W, wdec2T);
    stem1wt_k<<<38, 256, 0, stream>>>(stem1_W, wstem1);

    stem1_k<<<dim3(256, 32), 256, 0, stream>>>(x, wstem1, stem1_b, h1n);
    s2m_k<<<dim3(16, 32), 256, 0, stream>>>(h1n, w_stem2, stem2_b, h2_n);
    gauss_k<<<4096, 256, 0, stream>>>(h2_n, gauss_W, gauss_b, eps, zs_n, kl_out);
    pregates_k<<<dim3(8, 32), 256, 0, stream>>>(h2_n, w_pre, post_b, pregates);

    ushort_t* hq_in = hq_a; ushort_t* hq_out = hq_b;
    ushort_t* hp_in = hp_a; ushort_t* hp_out = hp_b;
    for (int s = 0; s < KSTEPS - 1; ++s){
        const ushort_t* zn_s = zs_n + (size_t)s * 1048576;
        qp_gconv_k<<<dim3(8, 32, 2), 256, 0, stream>>>(
            zn_s, hq_in, hp_in, w_post, w_prior, pregates, post_b, prior_b,
            cq, cp, hq_out, hp_out);
        postprior_k<<<4096, 256, 0, stream>>>(hq_out, hp_out,
            postlin_W, postlin_b, priorlin_W, priorlin_b,
            eps + (size_t)(s + 1) * 1048576,
            zs_n + (size_t)(s + 1) * 1048576, kl_out, s + 1);
        ushort_t* t;
        t = hq_in; hq_in = hq_out; hq_out = t;
        t = hp_in; hp_in = hp_out; hp_out = t;
    }

    for (int k = 0; k < KSTEPS; ++k){
        dec1m_k<<<dim3(16, 2, 32), 256, 0, stream>>>(zs_n + (size_t)k * 1048576, wdec1b, dec1_b, d1out);
        dec2t_k<<<dim3(8, 32), 256, 0, stream>>>(d1out, wdec2T, dec2_b, dco + (size_t)k * BATCH * 16384);
    }
    stick_k<<<2048, 256, 0, stream>>>(dco, lm_out);
}